// Round 5
// baseline (656.098 us; speedup 1.0000x reference)
//
#include <hip/hip_runtime.h>
#include <math.h>

// ResBlock via bf16 MFMA implicit-GEMM conv3x3, pipelined + T2-swizzled LDS.
// B=16, C=256, H=W=96. Padded channels-last bf16 intermediates [16][98][98][256].

#define Bn 16
#define Cn 256
#define Hn 96
#define Wn 96
#define PH 98
#define PW 98
#define HW (Hn*Wn)

typedef __bf16 bf16x8 __attribute__((ext_vector_type(8)));
typedef float  f32x4  __attribute__((ext_vector_type(4)));

__device__ __forceinline__ unsigned short f2bf(float f) {
    unsigned int u = __float_as_uint(f);
    unsigned int r = (u + 0x7fffu + ((u >> 16) & 1u)) >> 16;
    return (unsigned short)r;
}

__device__ __forceinline__ void lds_load16(void* lds, const void* g) {
    auto gp = (const __attribute__((address_space(1))) char*)(unsigned long long)(uintptr_t)g;
    auto lp = (__attribute__((address_space(3))) char*)(unsigned int)(uintptr_t)lds;
    __builtin_amdgcn_global_load_lds(gp, lp, 16, 0, 0);
}

#define SB() __builtin_amdgcn_sched_barrier(0)
#define MEMFENCE() asm volatile("" ::: "memory")

// ---- zero the padded border of a CL tensor ----
__global__ __launch_bounds__(256)
void zero_border_k(unsigned short* __restrict__ t) {
    int idx = blockIdx.x * 256 + threadIdx.x;      // 16*388*32 threads
    int oct = idx & 31;
    int rest = idx >> 5;
    int pidx = rest % 388;
    int b = rest / 388;
    int h, w;
    if (pidx < 98)       { h = 0;  w = pidx; }
    else if (pidx < 196) { h = 97; w = pidx - 98; }
    else if (pidx < 292) { h = pidx - 196 + 1; w = 0; }
    else                 { h = pidx - 292 + 1; w = 97; }
    size_t e = ((size_t)(b * PH + h) * PW + w) * 256 + oct * 8;
    *(uint4*)(t + e) = make_uint4(0u, 0u, 0u, 0u);
}

// ---- pack weights fp32 [co][ci][3][3] -> bf16 [cc][k9][c'][ci32] ----
template<bool PERM>
__global__ __launch_bounds__(256)
void pack_w_k(const float* __restrict__ w, unsigned short* __restrict__ wp) {
    int idx = blockIdx.x * 256 + threadIdx.x;      // 589824
    int ci_l = idx & 31;
    int c    = (idx >> 5) & 255;
    int v    = idx >> 13;          // 0..71
    int k9   = v % 9;
    int cc   = v / 9;
    int co;
    if (PERM) {
        co = (c < 86) ? c * 3 : (c < 171) ? (c - 86) * 3 + 1 : (c - 171) * 3 + 2;
    } else {
        co = c;
    }
    float val = w[((size_t)co * 256 + cc * 32 + ci_l) * 9 + k9];
    wp[idx] = f2bf(val);
}

// ---- x fp32 NCHW -> padded channels-last bf16 (interior only) ----
__global__ __launch_bounds__(256)
void transform_x_k(const float* __restrict__ x, unsigned short* __restrict__ xp) {
    __shared__ float s[32 * 33];
    const int t = threadIdx.x;
    const int col0 = blockIdx.x * 32;
    const int row  = blockIdx.y;
    const int z = blockIdx.z;
    const int b = z >> 3;
    const int ci0 = (z & 7) * 32;

    #pragma unroll
    for (int i = 0; i < 4; ++i) {
        int ci = i * 8 + (t >> 5);
        int px = t & 31;
        s[ci * 33 + px] = x[((size_t)(b * Cn + ci0 + ci)) * HW + row * Wn + col0 + px];
    }
    __syncthreads();
    const int px = t >> 3;
    const int c4 = (t & 7) * 4;
    ushort4 o;
    o.x = f2bf(s[(c4 + 0) * 33 + px]);
    o.y = f2bf(s[(c4 + 1) * 33 + px]);
    o.z = f2bf(s[(c4 + 2) * 33 + px]);
    o.w = f2bf(s[(c4 + 3) * 33 + px]);
    size_t e = ((size_t)(b * PH + row + 1) * PW + (col0 + px + 1)) * 256 + ci0 + c4;
    *(ushort4*)(xp + e) = o;
}

// ---- Pipelined MFMA conv3x3 ----
// 512 threads (8 waves), 1 block/CU. Block: 128 co x (12x32 px).
// s_x / s_w use the T2 XOR swizzle: phys16Bslot = log16Bslot ^ ((slot>>3)&3).
// s_x staged by gl_lds with PRE-SWIZZLED GLOBAL SOURCE (linear LDS dest);
// s_w reg-staged with swizzled ds_write dest. Reads apply the same involution.
// Compute: per-chunk 9 k9-steps, fragment A/B double-buffer (k9+1 ds_reads
// overlap k9 MFMAs), single setprio pair per chunk.
template<int MODE>
__global__ __launch_bounds__(512, 2)
void conv_k(const unsigned short* __restrict__ in_cl,
            const unsigned short* __restrict__ wp,
            const float* __restrict__ prelu_w,
            const float* __restrict__ xres,
            void* __restrict__ outp)
{
    __shared__ unsigned short s_x[2][2048 * 8];   // 2 x 32768 B  [px(14x34)][ci32]
    __shared__ unsigned short s_w[9 * 128 * 32];  // 73728 B      [k9][co128][ci32]

    const int tid = threadIdx.x;
    const int bid = blockIdx.x;
    // XCD-chunked bijective swizzle (768 = 8 * 96); co-half fastest.
    const int wg = (bid & 7) * 96 + (bid >> 3);
    const int blk_co = (wg & 1) * 128;
    const int t2 = wg >> 1;                // 0..383
    const int tile = t2 % 24;
    const int b = t2 / 24;
    const int R0 = (tile / 3) * 12;        // padded-coord halo base row
    const int C0 = (tile % 3) * 32;

    const int lane = tid & 63;
    const int wv = tid >> 6;
    const int l15 = lane & 15;
    const int qq = lane >> 4;
    const int cg = wv & 1;
    const int wrow = wv >> 1;
    const int qa = qq ^ ((l15 >> 1) & 3);  // swizzled 16B-slot for af reads

    const unsigned short* img = in_cl + (size_t)b * PH * PW * 256;

    // ---- staging maps ----
    // x: logical slots 0..1903 (476 px * 4 parts). gl_lds dest is linear
    // (slot = i*512+tid); the SOURCE uses the swizzle-inverse logical slot.
    int xg[4];
    #pragma unroll
    for (int i = 0; i < 4; ++i) {
        int slot = i * 512 + tid;
        int lsl = slot ^ ((slot >> 3) & 3);    // involution, preserves slot>>3
        if (lsl > 1903) lsl = 1903;            // junk phys slots read a safe dup
        int p = lsl >> 2;
        int pr = p / 34, pc = p - pr * 34;
        xg[i] = ((R0 + pr) * PW + (C0 + pc)) * 256 + (lsl & 3) * 8;
    }
    // w: 9*128*4 = 4608 slots, exactly 9/thread. Global read linear; LDS
    // write goes to the swizzled phys slot.
    int wgo[9], wlds[9];
    #pragma unroll
    for (int i = 0; i < 9; ++i) {
        int slot = i * 512 + tid;
        int k9 = slot >> 9;
        int co = (slot >> 2) & 127;
        wgo[i]  = (k9 * 256 + blk_co + co) * 32 + (slot & 3) * 8;
        wlds[i] = (slot ^ ((slot >> 3) & 3)) * 8;
    }

    f32x4 acc[4][6];
    #pragma unroll
    for (int m = 0; m < 4; ++m)
        #pragma unroll
        for (int n = 0; n < 6; ++n) acc[m][n] = 0.f;

    // ---- prologue ----
    // issue x(0) gl_lds, then rw(0) reg loads, then x(1) gl_lds
    #pragma unroll
    for (int i = 0; i < 4; ++i) lds_load16(&s_x[0][(size_t)(i * 512 + tid) * 8], img + xg[i]);
    uint4 rw[9];
    #pragma unroll
    for (int i = 0; i < 9; ++i) rw[i] = *(const uint4*)(wp + wgo[i]);
    MEMFENCE(); SB();
    #pragma unroll
    for (int i = 0; i < 4; ++i) lds_load16(&s_x[1][(size_t)(i * 512 + tid) * 8], img + xg[i] + 32);
    MEMFENCE(); SB();
    asm volatile("s_waitcnt vmcnt(4)" ::: "memory");   // x(0)+rw(0) landed; x(1) flies
    SB();
    #pragma unroll
    for (int i = 0; i < 9; ++i)
        *(uint4*)&s_w[wlds[i]] = rw[i];                // swizzled ds_write of w(0)
    MEMFENCE(); SB();
    #pragma unroll
    for (int i = 0; i < 9; ++i)
        rw[i] = *(const uint4*)(wp + 73728 + wgo[i]);  // w(1) -> regs
    MEMFENCE(); SB();
    asm volatile("s_waitcnt lgkmcnt(0)" ::: "memory"); // w(0) ds_writes visible
    SB();
    __builtin_amdgcn_s_barrier();
    SB();

    // fragment loaders (swizzled reads)
#define LOADF(AF, BF, K) {                                                        \
    const int kh_ = (K) / 3, kw_ = (K) - 3 * kh_;                                 \
    _Pragma("unroll")                                                             \
    for (int m = 0; m < 4; ++m) {                                                 \
        const int row_ = (K) * 128 + cg * 64 + m * 16 + l15;                      \
        AF[m] = *(const bf16x8*)&s_w[row_ * 32 + qa * 8];                         \
    }                                                                             \
    _Pragma("unroll")                                                             \
    for (int n = 0; n < 6; ++n) {                                                 \
        const int P_ = (wrow * 3 + (n >> 1) + kh_) * 34 + (n & 1) * 16 + l15 + kw_; \
        BF[n] = *(const bf16x8*)&sxc[P_ * 32 + ((qq ^ ((P_ >> 1) & 3)) << 3)];    \
    }                                                                             \
}
#define MFMA_ON(AF, BF) {                                                         \
    _Pragma("unroll")                                                             \
    for (int n = 0; n < 6; ++n)                                                   \
        _Pragma("unroll")                                                         \
        for (int m = 0; m < 4; ++m)                                               \
            acc[m][n] = __builtin_amdgcn_mfma_f32_16x16x32_bf16(AF[m], BF[n], acc[m][n], 0, 0, 0); \
}

    for (int c = 0; c < 8; ++c) {
        const unsigned short* sxc = s_x[c & 1];
        bf16x8 afA[4], bfA[6], afB[4], bfB[6];
        LOADF(afA, bfA, 0);
        __builtin_amdgcn_s_setprio(1);
        #pragma unroll
        for (int k9 = 0; k9 < 9; ++k9) {
            if ((k9 & 1) == 0) {
                if (k9 < 8) LOADF(afB, bfB, k9 + 1);
                MFMA_ON(afA, bfA);
            } else {
                LOADF(afA, bfA, k9 + 1);
                MFMA_ON(afB, bfB);
            }
        }
        __builtin_amdgcn_s_setprio(0);

        if (c < 7) {
            __builtin_amdgcn_s_barrier();               // all waves done with s_w / s_x[c&1]
            SB();
            asm volatile("s_waitcnt vmcnt(0)" ::: "memory");  // x(c+1) + rw(c+1) landed
            SB();
            #pragma unroll
            for (int i = 0; i < 9; ++i)
                *(uint4*)&s_w[wlds[i]] = rw[i];         // w(c+1) -> s_w (swizzled)
            MEMFENCE(); SB();
            if (c < 6) {
                const int cc2 = c + 2;
                #pragma unroll
                for (int i = 0; i < 4; ++i)
                    lds_load16(&s_x[c & 1][(size_t)(i * 512 + tid) * 8], img + xg[i] + cc2 * 32);
                MEMFENCE(); SB();
                #pragma unroll
                for (int i = 0; i < 9; ++i)
                    rw[i] = *(const uint4*)(wp + (size_t)cc2 * 73728 + wgo[i]);
                MEMFENCE(); SB();
            }
            asm volatile("s_waitcnt lgkmcnt(0)" ::: "memory");  // ds_writes visible
            SB();
            __builtin_amdgcn_s_barrier();
            SB();
        }
    }
#undef LOADF
#undef MFMA_ON

    // ---- epilogue (n-outer, m-inner for write combining) ----
    if constexpr (MODE == 0) {
        const float pw = prelu_w[0];
        unsigned short* aout = (unsigned short*)outp;
        #pragma unroll
        for (int n = 0; n < 6; ++n) {
            const int row_p = wrow * 3 + (n >> 1);
            const int col_p = (n & 1) * 16 + l15;
            size_t pix = ((size_t)(b * PH + R0 + row_p + 1)) * PW + (C0 + col_p + 1);
            #pragma unroll
            for (int m = 0; m < 4; ++m) {
                const int cb = blk_co + cg * 64 + m * 16 + qq * 4;
                float r[4];
                #pragma unroll
                for (int j = 0; j < 4; ++j) {
                    const int ch = cb + j;
                    float s = acc[m][n][j];
                    if (ch < 86)        r[j] = s >= 0.f ? s : pw * s;
                    else if (ch < 171)  r[j] = fmaxf(s, 0.f);
                    else {
                        float e = __expf(2.f * s);
                        r[j] = 1.f - 2.f / (e + 1.f);
                    }
                }
                ushort4 o;
                o.x = f2bf(r[0]); o.y = f2bf(r[1]); o.z = f2bf(r[2]); o.w = f2bf(r[3]);
                *(ushort4*)(aout + pix * 256 + cb) = o;
            }
        }
    } else {
        float* fout = (float*)outp;
        #pragma unroll
        for (int n = 0; n < 6; ++n) {
            const int row_p = wrow * 3 + (n >> 1);
            const int col_p = (n & 1) * 16 + l15;
            #pragma unroll
            for (int m = 0; m < 4; ++m) {
                const int cb = blk_co + cg * 64 + m * 16 + qq * 4;
                size_t base = ((size_t)(b * Cn + cb)) * HW + (size_t)(R0 + row_p) * Wn + (C0 + col_p);
                #pragma unroll
                for (int j = 0; j < 4; ++j)
                    fout[base + (size_t)j * HW] = acc[m][n][j] * 0.1f + xres[base + (size_t)j * HW];
            }
        }
    }
}

extern "C" void kernel_launch(void* const* d_in, const int* in_sizes, int n_in,
                              void* d_out, int out_size, void* d_ws, size_t ws_size,
                              hipStream_t stream) {
    const float* x  = (const float*)d_in[0];
    const float* w2 = (const float*)d_in[1];
    const float* w3 = (const float*)d_in[2];
    const float* pw = (const float*)d_in[3];
    float* out = (float*)d_out;
    char* ws = (char*)d_ws;

    // ws layout: a_cl (78,675,968 B) | wp2 (1,179,648 B) | wp3 (1,179,648 B)  = 81 MB
    unsigned short* a_cl = (unsigned short*)ws;
    unsigned short* wp2  = (unsigned short*)(ws + 78675968);
    unsigned short* wp3  = (unsigned short*)(ws + 78675968 + 1179648);
    // x_pad aliases d_out (78.7 MB <= 151 MB); dead before conv<1> writes d_out.
    unsigned short* x_pad = (unsigned short*)d_out;

    zero_border_k<<<776, 256, 0, stream>>>(x_pad);
    zero_border_k<<<776, 256, 0, stream>>>(a_cl);
    pack_w_k<true ><<<2304, 256, 0, stream>>>(w2, wp2);
    pack_w_k<false><<<2304, 256, 0, stream>>>(w3, wp3);
    transform_x_k<<<dim3(3, 96, 128), 256, 0, stream>>>(x, x_pad);

    conv_k<0><<<768, 512, 0, stream>>>(x_pad, wp2, pw, nullptr, (void*)a_cl);
    conv_k<1><<<768, 512, 0, stream>>>(a_cl, wp3, nullptr, x, (void*)out);
}

// Round 6
// 406.394 us; speedup vs baseline: 1.6144x; 1.6144x over previous
//
#include <hip/hip_runtime.h>
#include <math.h>

// ResBlock via bf16 MFMA implicit-GEMM conv3x3.
// Pipelined schedule, T2-swizzled LDS, NO long-lived register staging
// (R5 post-mortem: rw[] spill -> scratch churn was the bottleneck).
// B=16, C=256, H=W=96. Padded channels-last bf16 intermediates [16][98][98][256].

#define Bn 16
#define Cn 256
#define Hn 96
#define Wn 96
#define PH 98
#define PW 98
#define HW (Hn*Wn)

typedef __bf16 bf16x8 __attribute__((ext_vector_type(8)));
typedef float  f32x4  __attribute__((ext_vector_type(4)));

__device__ __forceinline__ unsigned short f2bf(float f) {
    unsigned int u = __float_as_uint(f);
    unsigned int r = (u + 0x7fffu + ((u >> 16) & 1u)) >> 16;
    return (unsigned short)r;
}

__device__ __forceinline__ void lds_load16(void* lds, const void* g) {
    auto gp = (const __attribute__((address_space(1))) char*)(unsigned long long)(uintptr_t)g;
    auto lp = (__attribute__((address_space(3))) char*)(unsigned int)(uintptr_t)lds;
    __builtin_amdgcn_global_load_lds(gp, lp, 16, 0, 0);
}

#define SB() __builtin_amdgcn_sched_barrier(0)
#define MEMFENCE() asm volatile("" ::: "memory")

// ---- zero the padded border of a CL tensor ----
__global__ __launch_bounds__(256)
void zero_border_k(unsigned short* __restrict__ t) {
    int idx = blockIdx.x * 256 + threadIdx.x;      // 16*388*32 threads
    int oct = idx & 31;
    int rest = idx >> 5;
    int pidx = rest % 388;
    int b = rest / 388;
    int h, w;
    if (pidx < 98)       { h = 0;  w = pidx; }
    else if (pidx < 196) { h = 97; w = pidx - 98; }
    else if (pidx < 292) { h = pidx - 196 + 1; w = 0; }
    else                 { h = pidx - 292 + 1; w = 97; }
    size_t e = ((size_t)(b * PH + h) * PW + w) * 256 + oct * 8;
    *(uint4*)(t + e) = make_uint4(0u, 0u, 0u, 0u);
}

// ---- pack weights fp32 [co][ci][3][3] -> bf16 [cc][k9][c'][ci32] ----
template<bool PERM>
__global__ __launch_bounds__(256)
void pack_w_k(const float* __restrict__ w, unsigned short* __restrict__ wp) {
    int idx = blockIdx.x * 256 + threadIdx.x;      // 589824
    int ci_l = idx & 31;
    int c    = (idx >> 5) & 255;
    int v    = idx >> 13;          // 0..71
    int k9   = v % 9;
    int cc   = v / 9;
    int co;
    if (PERM) {
        co = (c < 86) ? c * 3 : (c < 171) ? (c - 86) * 3 + 1 : (c - 171) * 3 + 2;
    } else {
        co = c;
    }
    float val = w[((size_t)co * 256 + cc * 32 + ci_l) * 9 + k9];
    wp[idx] = f2bf(val);
}

// ---- x fp32 NCHW -> padded channels-last bf16 (interior only) ----
__global__ __launch_bounds__(256)
void transform_x_k(const float* __restrict__ x, unsigned short* __restrict__ xp) {
    __shared__ float s[32 * 33];
    const int t = threadIdx.x;
    const int col0 = blockIdx.x * 32;
    const int row  = blockIdx.y;
    const int z = blockIdx.z;
    const int b = z >> 3;
    const int ci0 = (z & 7) * 32;

    #pragma unroll
    for (int i = 0; i < 4; ++i) {
        int ci = i * 8 + (t >> 5);
        int px = t & 31;
        s[ci * 33 + px] = x[((size_t)(b * Cn + ci0 + ci)) * HW + row * Wn + col0 + px];
    }
    __syncthreads();
    const int px = t >> 3;
    const int c4 = (t & 7) * 4;
    ushort4 o;
    o.x = f2bf(s[(c4 + 0) * 33 + px]);
    o.y = f2bf(s[(c4 + 1) * 33 + px]);
    o.z = f2bf(s[(c4 + 2) * 33 + px]);
    o.w = f2bf(s[(c4 + 3) * 33 + px]);
    size_t e = ((size_t)(b * PH + row + 1) * PW + (col0 + px + 1)) * 256 + ci0 + c4;
    *(ushort4*)(xp + e) = o;
}

// ---- Pipelined MFMA conv3x3 ----
// 512 threads (8 waves), 1 block/CU. Block: 128 co x (12x32 px).
// s_x double-buffered, s_w single-buffered; BOTH staged purely by
// global_load_lds with PRE-SWIZZLED GLOBAL SOURCE (linear LDS dest, rule #21);
// reads apply the same involution: phys16Bslot = logical ^ ((logical>>3)&3).
// Tail per chunk: barrier; issue w(c+1) gl_lds; issue x(c+2) gl_lds;
// vmcnt(4) (drains w(c+1)+x(c+1), leaves x(c+2) flying); barrier.
// No registers live across the compute phase except acc[4][6].
template<int MODE>
__global__ __launch_bounds__(512, 2)
void conv_k(const unsigned short* __restrict__ in_cl,
            const unsigned short* __restrict__ wp,
            const float* __restrict__ prelu_w,
            const float* __restrict__ xres,
            void* __restrict__ outp)
{
    __shared__ unsigned short s_x[2][2048 * 8];   // 2 x 32768 B  [px(14x34)][ci32]
    __shared__ unsigned short s_w[9 * 128 * 32];  // 73728 B      [k9][co128][ci32]

    const int tid = threadIdx.x;
    const int bid = blockIdx.x;
    // XCD-chunked bijective swizzle (768 = 8 * 96); co-half fastest.
    const int wg = (bid & 7) * 96 + (bid >> 3);
    const int blk_co = (wg & 1) * 128;
    const int t2 = wg >> 1;                // 0..383
    const int tile = t2 % 24;
    const int b = t2 / 24;
    const int R0 = (tile / 3) * 12;        // padded-coord halo base row
    const int C0 = (tile % 3) * 32;

    const int lane = tid & 63;
    const int wv = tid >> 6;
    const int l15 = lane & 15;
    const int qq = lane >> 4;
    const int cg = wv & 1;
    const int wrow = wv >> 1;
    const int qa = qq ^ ((l15 >> 1) & 3);  // swizzled 16B-slot for af reads

    const unsigned short* img = in_cl + (size_t)b * PH * PW * 256;

    // ---- staging maps (gl_lds dest linear = i*512+tid; source pre-swizzled) ----
    // x: logical slots 0..1903 (476 px * 4 parts)
    int xg[4];
    #pragma unroll
    for (int i = 0; i < 4; ++i) {
        int slot = i * 512 + tid;
        int lsl = slot ^ ((slot >> 3) & 3);    // involution, preserves slot>>3
        if (lsl > 1903) lsl = 1903;            // junk phys slots read a safe dup
        int p = lsl >> 2;
        int pr = p / 34, pc = p - pr * 34;
        xg[i] = ((R0 + pr) * PW + (C0 + pc)) * 256 + (lsl & 3) * 8;
    }
    // w: 9*128*4 = 4608 slots, exactly 9/thread
    int wgo[9];
    #pragma unroll
    for (int i = 0; i < 9; ++i) {
        int slot = i * 512 + tid;
        int lsl = slot ^ ((slot >> 3) & 3);    // stays in [0,4608)
        int k9 = lsl >> 9;
        int co = (lsl >> 2) & 127;
        wgo[i] = (k9 * 256 + blk_co + co) * 32 + (lsl & 3) * 8;
    }

    f32x4 acc[4][6];
    #pragma unroll
    for (int m = 0; m < 4; ++m)
        #pragma unroll
        for (int n = 0; n < 6; ++n) acc[m][n] = 0.f;

    // ---- prologue: x(0), w(0), x(1) all via gl_lds ----
    #pragma unroll
    for (int i = 0; i < 4; ++i) lds_load16(&s_x[0][(size_t)(i * 512 + tid) * 8], img + xg[i]);
    #pragma unroll
    for (int i = 0; i < 9; ++i) lds_load16(&s_w[(size_t)(i * 512 + tid) * 8], wp + wgo[i]);
    MEMFENCE(); SB();
    #pragma unroll
    for (int i = 0; i < 4; ++i) lds_load16(&s_x[1][(size_t)(i * 512 + tid) * 8], img + xg[i] + 32);
    MEMFENCE(); SB();
    asm volatile("s_waitcnt vmcnt(4)" ::: "memory");   // x(0)+w(0) landed; x(1) flies
    SB();
    __builtin_amdgcn_s_barrier();
    SB();

#define LOADF(AF, BF, K) {                                                        \
    const int kh_ = (K) / 3, kw_ = (K) - 3 * kh_;                                 \
    _Pragma("unroll")                                                             \
    for (int m = 0; m < 4; ++m) {                                                 \
        const int row_ = (K) * 128 + cg * 64 + m * 16 + l15;                      \
        AF[m] = *(const bf16x8*)&s_w[row_ * 32 + qa * 8];                         \
    }                                                                             \
    _Pragma("unroll")                                                             \
    for (int n = 0; n < 6; ++n) {                                                 \
        const int P_ = (wrow * 3 + (n >> 1) + kh_) * 34 + (n & 1) * 16 + l15 + kw_; \
        BF[n] = *(const bf16x8*)&sxc[P_ * 32 + ((qq ^ ((P_ >> 1) & 3)) << 3)];    \
    }                                                                             \
}
#define MFMA_ON(AF, BF) {                                                         \
    _Pragma("unroll")                                                             \
    for (int n = 0; n < 6; ++n)                                                   \
        _Pragma("unroll")                                                         \
        for (int m = 0; m < 4; ++m)                                               \
            acc[m][n] = __builtin_amdgcn_mfma_f32_16x16x32_bf16(AF[m], BF[n], acc[m][n], 0, 0, 0); \
}

    for (int c = 0; c < 8; ++c) {
        const unsigned short* sxc = s_x[c & 1];
        __builtin_amdgcn_s_setprio(1);
        #pragma unroll
        for (int k9 = 0; k9 < 9; ++k9) {
            bf16x8 af[4], bf[6];
            LOADF(af, bf, k9);
            MFMA_ON(af, bf);
        }
        __builtin_amdgcn_s_setprio(0);

        if (c < 7) {
            __builtin_amdgcn_s_barrier();               // all waves done with s_w / s_x[c&1]
            SB();
            // stream w(c+1) into s_w (L2-resident after round 1)
            #pragma unroll
            for (int i = 0; i < 9; ++i)
                lds_load16(&s_w[(size_t)(i * 512 + tid) * 8],
                           wp + (size_t)(c + 1) * 73728 + wgo[i]);
            MEMFENCE(); SB();
            if (c < 6) {
                #pragma unroll
                for (int i = 0; i < 4; ++i)
                    lds_load16(&s_x[c & 1][(size_t)(i * 512 + tid) * 8],
                               img + xg[i] + (c + 2) * 32);
                MEMFENCE(); SB();
                asm volatile("s_waitcnt vmcnt(4)" ::: "memory");  // w(c+1)+x(c+1) done; x(c+2) flies
            } else {
                asm volatile("s_waitcnt vmcnt(0)" ::: "memory");
            }
            SB();
            __builtin_amdgcn_s_barrier();
            SB();
        }
    }
#undef LOADF
#undef MFMA_ON

    // ---- epilogue (n-outer, m-inner for write combining) ----
    if constexpr (MODE == 0) {
        const float pw = prelu_w[0];
        unsigned short* aout = (unsigned short*)outp;
        #pragma unroll
        for (int n = 0; n < 6; ++n) {
            const int row_p = wrow * 3 + (n >> 1);
            const int col_p = (n & 1) * 16 + l15;
            size_t pix = ((size_t)(b * PH + R0 + row_p + 1)) * PW + (C0 + col_p + 1);
            #pragma unroll
            for (int m = 0; m < 4; ++m) {
                const int cb = blk_co + cg * 64 + m * 16 + qq * 4;
                float r[4];
                #pragma unroll
                for (int j = 0; j < 4; ++j) {
                    const int ch = cb + j;
                    float s = acc[m][n][j];
                    if (ch < 86)        r[j] = s >= 0.f ? s : pw * s;
                    else if (ch < 171)  r[j] = fmaxf(s, 0.f);
                    else {
                        float e = __expf(2.f * s);
                        r[j] = 1.f - 2.f / (e + 1.f);
                    }
                }
                ushort4 o;
                o.x = f2bf(r[0]); o.y = f2bf(r[1]); o.z = f2bf(r[2]); o.w = f2bf(r[3]);
                *(ushort4*)(aout + pix * 256 + cb) = o;
            }
        }
    } else {
        float* fout = (float*)outp;
        #pragma unroll
        for (int n = 0; n < 6; ++n) {
            const int row_p = wrow * 3 + (n >> 1);
            const int col_p = (n & 1) * 16 + l15;
            #pragma unroll
            for (int m = 0; m < 4; ++m) {
                const int cb = blk_co + cg * 64 + m * 16 + qq * 4;
                size_t base = ((size_t)(b * Cn + cb)) * HW + (size_t)(R0 + row_p) * Wn + (C0 + col_p);
                #pragma unroll
                for (int j = 0; j < 4; ++j)
                    fout[base + (size_t)j * HW] = acc[m][n][j] * 0.1f + xres[base + (size_t)j * HW];
            }
        }
    }
}

extern "C" void kernel_launch(void* const* d_in, const int* in_sizes, int n_in,
                              void* d_out, int out_size, void* d_ws, size_t ws_size,
                              hipStream_t stream) {
    const float* x  = (const float*)d_in[0];
    const float* w2 = (const float*)d_in[1];
    const float* w3 = (const float*)d_in[2];
    const float* pw = (const float*)d_in[3];
    float* out = (float*)d_out;
    char* ws = (char*)d_ws;

    // ws layout: a_cl (78,675,968 B) | wp2 (1,179,648 B) | wp3 (1,179,648 B)  = 81 MB
    unsigned short* a_cl = (unsigned short*)ws;
    unsigned short* wp2  = (unsigned short*)(ws + 78675968);
    unsigned short* wp3  = (unsigned short*)(ws + 78675968 + 1179648);
    // x_pad aliases d_out (78.7 MB <= 151 MB); dead before conv<1> writes d_out.
    unsigned short* x_pad = (unsigned short*)d_out;

    zero_border_k<<<776, 256, 0, stream>>>(x_pad);
    zero_border_k<<<776, 256, 0, stream>>>(a_cl);
    pack_w_k<true ><<<2304, 256, 0, stream>>>(w2, wp2);
    pack_w_k<false><<<2304, 256, 0, stream>>>(w3, wp3);
    transform_x_k<<<dim3(3, 96, 128), 256, 0, stream>>>(x, x_pad);

    conv_k<0><<<768, 512, 0, stream>>>(x_pad, wp2, pw, nullptr, (void*)a_cl);
    conv_k<1><<<768, 512, 0, stream>>>(a_cl, wp3, nullptr, x, (void*)out);
}

// Round 8
// 405.578 us; speedup vs baseline: 1.6177x; 1.0020x over previous
//
#include <hip/hip_runtime.h>
#include <math.h>

// ResBlock via bf16 MFMA implicit-GEMM conv3x3.
// R8 = R7 with the weight-staging stride bug fixed: global kh-step stride is
// 24576 ushorts (3 k9 blocks x 256 co x 32 ci), NOT the 12288-ushort LDS
// sub-chunk size. R7's s*12288 read wrong weights for every s>0.
// Design: fully double-buffered (s_x per ci-chunk, s_w per (ci,kh) sub-step),
// 24 sub-step pipeline with counted vmcnt; fragment A/B ping-pong;
// amdgpu_waves_per_eu(2,2) to unlock the 256-VGPR budget.
// B=16, C=256, H=W=96. Padded channels-last bf16 intermediates [16][98][98][256].

#define Bn 16
#define Cn 256
#define Hn 96
#define Wn 96
#define PH 98
#define PW 98
#define HW (Hn*Wn)

typedef __bf16 bf16x8 __attribute__((ext_vector_type(8)));
typedef float  f32x4  __attribute__((ext_vector_type(4)));

__device__ __forceinline__ unsigned short f2bf(float f) {
    unsigned int u = __float_as_uint(f);
    unsigned int r = (u + 0x7fffu + ((u >> 16) & 1u)) >> 16;
    return (unsigned short)r;
}

__device__ __forceinline__ void lds_load16(void* lds, const void* g) {
    auto gp = (const __attribute__((address_space(1))) char*)(unsigned long long)(uintptr_t)g;
    auto lp = (__attribute__((address_space(3))) char*)(unsigned int)(uintptr_t)lds;
    __builtin_amdgcn_global_load_lds(gp, lp, 16, 0, 0);
}

#define SB() __builtin_amdgcn_sched_barrier(0)
#define MEMFENCE() asm volatile("" ::: "memory")

// ---- zero the padded border of a CL tensor ----
__global__ __launch_bounds__(256)
void zero_border_k(unsigned short* __restrict__ t) {
    int idx = blockIdx.x * 256 + threadIdx.x;      // 16*388*32 threads
    int oct = idx & 31;
    int rest = idx >> 5;
    int pidx = rest % 388;
    int b = rest / 388;
    int h, w;
    if (pidx < 98)       { h = 0;  w = pidx; }
    else if (pidx < 196) { h = 97; w = pidx - 98; }
    else if (pidx < 292) { h = pidx - 196 + 1; w = 0; }
    else                 { h = pidx - 292 + 1; w = 97; }
    size_t e = ((size_t)(b * PH + h) * PW + w) * 256 + oct * 8;
    *(uint4*)(t + e) = make_uint4(0u, 0u, 0u, 0u);
}

// ---- pack weights fp32 [co][ci][3][3] -> bf16 [cc][k9][c'][ci32] ----
template<bool PERM>
__global__ __launch_bounds__(256)
void pack_w_k(const float* __restrict__ w, unsigned short* __restrict__ wp) {
    int idx = blockIdx.x * 256 + threadIdx.x;      // 589824
    int ci_l = idx & 31;
    int c    = (idx >> 5) & 255;
    int v    = idx >> 13;          // 0..71
    int k9   = v % 9;
    int cc   = v / 9;
    int co;
    if (PERM) {
        co = (c < 86) ? c * 3 : (c < 171) ? (c - 86) * 3 + 1 : (c - 171) * 3 + 2;
    } else {
        co = c;
    }
    float val = w[((size_t)co * 256 + cc * 32 + ci_l) * 9 + k9];
    wp[idx] = f2bf(val);
}

// ---- x fp32 NCHW -> padded channels-last bf16 (interior only) ----
__global__ __launch_bounds__(256)
void transform_x_k(const float* __restrict__ x, unsigned short* __restrict__ xp) {
    __shared__ float s[32 * 33];
    const int t = threadIdx.x;
    const int col0 = blockIdx.x * 32;
    const int row  = blockIdx.y;
    const int z = blockIdx.z;
    const int b = z >> 3;
    const int ci0 = (z & 7) * 32;

    #pragma unroll
    for (int i = 0; i < 4; ++i) {
        int ci = i * 8 + (t >> 5);
        int px = t & 31;
        s[ci * 33 + px] = x[((size_t)(b * Cn + ci0 + ci)) * HW + row * Wn + col0 + px];
    }
    __syncthreads();
    const int px = t >> 3;
    const int c4 = (t & 7) * 4;
    ushort4 o;
    o.x = f2bf(s[(c4 + 0) * 33 + px]);
    o.y = f2bf(s[(c4 + 1) * 33 + px]);
    o.z = f2bf(s[(c4 + 2) * 33 + px]);
    o.w = f2bf(s[(c4 + 3) * 33 + px]);
    size_t e = ((size_t)(b * PH + row + 1) * PW + (col0 + px + 1)) * 256 + ci0 + c4;
    *(ushort4*)(xp + e) = o;
}

// ---- Pipelined MFMA conv3x3 ----
// 512 threads (8 waves), 1 block/CU. Block: 128 co x (12x32 px).
// K-loop = 24 sub-steps s = (ci-chunk c, kh): s_w[2] holds one (c,kh)
// sub-chunk [kw3][co128][ci32] (24.6 KB), s_x[2] one ci-chunk (32.8 KB).
// All staging via global_load_lds with PRE-SWIZZLED SOURCE (rule #21),
// involution phys16Bslot = logical ^ ((logical>>3)&3) on both tensors.
// Per sub-step: issue w(s+1) [3 gl_lds]; if kh==1: issue x(c+1) [4 gl_lds];
// compute 3 kw steps (frag A/B ping-pong); vmcnt(4 or 0); s_barrier.
template<int MODE>
__global__ __launch_bounds__(512) __attribute__((amdgpu_waves_per_eu(2, 2)))
void conv_k(const unsigned short* __restrict__ in_cl,
            const unsigned short* __restrict__ wp,
            const float* __restrict__ prelu_w,
            const float* __restrict__ xres,
            void* __restrict__ outp)
{
    __shared__ unsigned short s_x[2][2048 * 8];   // 2 x 32768 B [px(14x34)][ci32]
    __shared__ unsigned short s_w[2][1536 * 8];   // 2 x 24576 B [kw3][co128][ci32]

    const int tid = threadIdx.x;
    const int bid = blockIdx.x;
    // XCD-chunked bijective swizzle (768 = 8 * 96); co-half fastest.
    const int wg = (bid & 7) * 96 + (bid >> 3);
    const int blk_co = (wg & 1) * 128;
    const int t2 = wg >> 1;                // 0..383
    const int tile = t2 % 24;
    const int b = t2 / 24;
    const int R0 = (tile / 3) * 12;        // padded-coord halo base row
    const int C0 = (tile % 3) * 32;

    const int lane = tid & 63;
    const int wv = tid >> 6;
    const int l15 = lane & 15;
    const int qq = lane >> 4;
    const int cg = wv & 1;
    const int wrow = wv >> 1;
    const int qa = qq ^ ((l15 >> 1) & 3);  // swizzled 16B-slot for af reads

    const unsigned short* img = in_cl + (size_t)b * PH * PW * 256;

    // ---- staging maps (gl_lds dest linear = i*512+tid; source pre-swizzled) ----
    // x: logical slots 0..1903 (476 px * 4 parts)
    int xg[4];
    #pragma unroll
    for (int i = 0; i < 4; ++i) {
        int slot = i * 512 + tid;
        int lsl = slot ^ ((slot >> 3) & 3);    // involution, preserves slot>>3
        if (lsl > 1903) lsl = 1903;            // junk phys slots read a safe dup
        int p = lsl >> 2;
        int pr = p / 34, pc = p - pr * 34;
        xg[i] = ((R0 + pr) * PW + (C0 + pc)) * 256 + (lsl & 3) * 8;
    }
    // w sub-chunk: 3 kw * 128 co * 4 parts = 1536 slots, 3/thread
    int wbase[3];
    #pragma unroll
    for (int i = 0; i < 3; ++i) {
        int slot = i * 512 + tid;
        int lsl = slot ^ ((slot >> 3) & 3);    // stays in [0,1536)
        int kw = lsl >> 9;
        int co = (lsl >> 2) & 127;
        wbase[i] = kw * 8192 + (blk_co + co) * 32 + (lsl & 3) * 8;
    }

    f32x4 acc[4][6];
    #pragma unroll
    for (int m = 0; m < 4; ++m)
        #pragma unroll
        for (int n = 0; n < 6; ++n) acc[m][n] = 0.f;

    // ---- prologue: w(s=0) + x(c=0) ----
    #pragma unroll
    for (int i = 0; i < 3; ++i) lds_load16(&s_w[0][(size_t)(i * 512 + tid) * 8], wp + wbase[i]);
    #pragma unroll
    for (int i = 0; i < 4; ++i) lds_load16(&s_x[0][(size_t)(i * 512 + tid) * 8], img + xg[i]);
    MEMFENCE(); SB();
    asm volatile("s_waitcnt vmcnt(0)" ::: "memory");
    SB();
    __builtin_amdgcn_s_barrier();
    SB();

#define LOADW(AF, KW) {                                                           \
    _Pragma("unroll")                                                             \
    for (int m = 0; m < 4; ++m) {                                                 \
        const int row_ = (KW) * 128 + cg * 64 + m * 16 + l15;                     \
        AF[m] = *(const bf16x8*)&swc[row_ * 32 + qa * 8];                         \
    }                                                                             \
}
#define LOADX(BF, KW) {                                                           \
    _Pragma("unroll")                                                             \
    for (int n = 0; n < 6; ++n) {                                                 \
        const int P_ = (wrow * 3 + (n >> 1) + kh) * 34 + (n & 1) * 16 + l15 + (KW); \
        BF[n] = *(const bf16x8*)&sxc[P_ * 32 + ((qq ^ ((P_ >> 1) & 3)) << 3)];    \
    }                                                                             \
}
#define MFMA_ON(AF, BF) {                                                         \
    __builtin_amdgcn_s_setprio(1);                                                \
    _Pragma("unroll")                                                             \
    for (int n = 0; n < 6; ++n)                                                   \
        _Pragma("unroll")                                                         \
        for (int m = 0; m < 4; ++m)                                               \
            acc[m][n] = __builtin_amdgcn_mfma_f32_16x16x32_bf16(AF[m], BF[n], acc[m][n], 0, 0, 0); \
    __builtin_amdgcn_s_setprio(0);                                                \
}

    for (int s = 0; s < 24; ++s) {
        const int c  = s / 3;
        const int kh = s - 3 * c;
        const unsigned short* swc = s_w[s & 1];
        const unsigned short* sxc = s_x[c & 1];
        const bool stage_x = (kh == 1) && (c < 7);

        // ---- issue next staging (w first, then x: FIFO order for vmcnt) ----
        if (s < 23) {
            // global kh-step stride = 3 k9 blocks x 256 co x 32 ci = 24576 ushorts
            #pragma unroll
            for (int i = 0; i < 3; ++i)
                lds_load16(&s_w[(s + 1) & 1][(size_t)(i * 512 + tid) * 8],
                           wp + (size_t)(s + 1) * 24576 + wbase[i]);
            MEMFENCE(); SB();
        }
        if (stage_x) {
            #pragma unroll
            for (int i = 0; i < 4; ++i)
                lds_load16(&s_x[(c + 1) & 1][(size_t)(i * 512 + tid) * 8],
                           img + xg[i] + (c + 1) * 32);
            MEMFENCE(); SB();
        }

        // ---- compute: 3 kw steps, frag A/B ping-pong ----
        {
            bf16x8 afA[4], bfA[6], afB[4], bfB[6];
            LOADW(afA, 0); LOADX(bfA, 0);
            LOADW(afB, 1); LOADX(bfB, 1);
            MFMA_ON(afA, bfA);
            LOADW(afA, 2); LOADX(bfA, 2);
            MFMA_ON(afB, bfB);
            MFMA_ON(afA, bfA);
        }

        // ---- boundary: drain w(s+1) (and x at chunk edges), keep newest x flying ----
        if (stage_x) {
            asm volatile("s_waitcnt vmcnt(4)" ::: "memory");
        } else {
            asm volatile("s_waitcnt vmcnt(0)" ::: "memory");
        }
        SB();
        __builtin_amdgcn_s_barrier();
        SB();
    }
#undef LOADW
#undef LOADX
#undef MFMA_ON

    // ---- epilogue (n-outer, m-inner for write combining) ----
    if constexpr (MODE == 0) {
        const float pw = prelu_w[0];
        unsigned short* aout = (unsigned short*)outp;
        #pragma unroll
        for (int n = 0; n < 6; ++n) {
            const int row_p = wrow * 3 + (n >> 1);
            const int col_p = (n & 1) * 16 + l15;
            size_t pix = ((size_t)(b * PH + R0 + row_p + 1)) * PW + (C0 + col_p + 1);
            #pragma unroll
            for (int m = 0; m < 4; ++m) {
                const int cb = blk_co + cg * 64 + m * 16 + qq * 4;
                float r[4];
                #pragma unroll
                for (int j = 0; j < 4; ++j) {
                    const int ch = cb + j;
                    float s = acc[m][n][j];
                    if (ch < 86)        r[j] = s >= 0.f ? s : pw * s;
                    else if (ch < 171)  r[j] = fmaxf(s, 0.f);
                    else {
                        float e = __expf(2.f * s);
                        r[j] = 1.f - 2.f / (e + 1.f);
                    }
                }
                ushort4 o;
                o.x = f2bf(r[0]); o.y = f2bf(r[1]); o.z = f2bf(r[2]); o.w = f2bf(r[3]);
                *(ushort4*)(aout + pix * 256 + cb) = o;
            }
        }
    } else {
        float* fout = (float*)outp;
        #pragma unroll
        for (int n = 0; n < 6; ++n) {
            const int row_p = wrow * 3 + (n >> 1);
            const int col_p = (n & 1) * 16 + l15;
            #pragma unroll
            for (int m = 0; m < 4; ++m) {
                const int cb = blk_co + cg * 64 + m * 16 + qq * 4;
                size_t base = ((size_t)(b * Cn + cb)) * HW + (size_t)(R0 + row_p) * Wn + (C0 + col_p);
                #pragma unroll
                for (int j = 0; j < 4; ++j)
                    fout[base + (size_t)j * HW] = acc[m][n][j] * 0.1f + xres[base + (size_t)j * HW];
            }
        }
    }
}

extern "C" void kernel_launch(void* const* d_in, const int* in_sizes, int n_in,
                              void* d_out, int out_size, void* d_ws, size_t ws_size,
                              hipStream_t stream) {
    const float* x  = (const float*)d_in[0];
    const float* w2 = (const float*)d_in[1];
    const float* w3 = (const float*)d_in[2];
    const float* pw = (const float*)d_in[3];
    float* out = (float*)d_out;
    char* ws = (char*)d_ws;

    // ws layout: a_cl (78,675,968 B) | wp2 (1,179,648 B) | wp3 (1,179,648 B)  = 81 MB
    unsigned short* a_cl = (unsigned short*)ws;
    unsigned short* wp2  = (unsigned short*)(ws + 78675968);
    unsigned short* wp3  = (unsigned short*)(ws + 78675968 + 1179648);
    // x_pad aliases d_out (78.7 MB <= 151 MB); dead before conv<1> writes d_out.
    unsigned short* x_pad = (unsigned short*)d_out;

    zero_border_k<<<776, 256, 0, stream>>>(x_pad);
    zero_border_k<<<776, 256, 0, stream>>>(a_cl);
    pack_w_k<true ><<<2304, 256, 0, stream>>>(w2, wp2);
    pack_w_k<false><<<2304, 256, 0, stream>>>(w3, wp3);
    transform_x_k<<<dim3(3, 96, 128), 256, 0, stream>>>(x, x_pad);

    conv_k<0><<<768, 512, 0, stream>>>(x_pad, wp2, pw, nullptr, (void*)a_cl);
    conv_k<1><<<768, 512, 0, stream>>>(a_cl, wp3, nullptr, x, (void*)out);
}